// Round 5
// baseline (185.050 us; speedup 1.0000x reference)
//
#include <hip/hip_runtime.h>
#include <math.h>

typedef unsigned long long u64;
typedef unsigned int u32;

#define NB   2
#define L0   4800
#define L1   4800
#define H1C  60
#define W1C  80
#define ROWS 16
#define RG   (L0 / ROWS)          // 300 row-groups per batch
#define JS   8                    // j-range split
#define CH4  (L1 / 2 / JS)        // 300*2=600/... = 300? no: L1/2=2400 float4; /8 = 300
#define NBLK (NB * RG * JS)       // 2 * 300 * 8 = 4800 blocks
#define NROW (NB * L0)            // 9600 output rows
// ws: [0..4)=counter, [256..256+NROW*8*8)=slots[row][chunk] u64

__global__ void s2ld_main(
    const float* __restrict__ w_pt0,    // [NB][L0][2]
    const float* __restrict__ pt1,      // [NB][L1][2]
    const void*  __restrict__ maskp,    // [NB][L0] word- or byte-bool
    const float* __restrict__ score0,   // [NB][L0]
    const float* __restrict__ score1,   // [NB][L1]
    const float* __restrict__ scale0,   // [NB][2]
    const float* __restrict__ scale1,   // [NB][2]
    u64*         __restrict__ slots,    // [NROW][JS]
    u32*         __restrict__ counter,
    float*       __restrict__ out)      // [3]
{
    __shared__ float redd[ROWS * 4];
    __shared__ int   redj[ROWS * 4];
    __shared__ float fin[12 * 4];
    __shared__ int   slast;
    __shared__ u32   sbad;

    const int tid  = threadIdx.x;
    const int blk  = blockIdx.x;
    const int n    = blk / (RG * JS);
    const int rem  = blk - n * (RG * JS);
    const int rg   = rem / JS;          // row-group within batch
    const int c    = rem - rg * JS;     // j-chunk 0..7
    const int lane = tid & 63;
    const int wv   = tid >> 6;
    const int gi0  = n * L0 + rg * ROWS;    // first global row of this block

    const float4* p1 = (const float4*)(pt1 + (size_t)n * L1 * 2);
    const float4* p0 = (const float4*)(w_pt0 + (size_t)gi0 * 2);  // 8 float4

    // 16 query points as NAMED scalars only (no arrays -> no scratch demotion)
    float px0,px1,px2,px3,px4,px5,px6,px7,px8,px9,px10,px11,px12,px13,px14,px15;
    float py0,py1,py2,py3,py4,py5,py6,py7,py8,py9,py10,py11,py12,py13,py14,py15;
    {
        float4 f;
        f=p0[0]; px0 =f.x; py0 =f.y; px1 =f.z; py1 =f.w;
        f=p0[1]; px2 =f.x; py2 =f.y; px3 =f.z; py3 =f.w;
        f=p0[2]; px4 =f.x; py4 =f.y; px5 =f.z; py5 =f.w;
        f=p0[3]; px6 =f.x; py6 =f.y; px7 =f.z; py7 =f.w;
        f=p0[4]; px8 =f.x; py8 =f.y; px9 =f.z; py9 =f.w;
        f=p0[5]; px10=f.x; py10=f.y; px11=f.z; py11=f.w;
        f=p0[6]; px12=f.x; py12=f.y; px13=f.z; py13=f.w;
        f=p0[7]; px14=f.x; py14=f.y; px15=f.z; py15=f.w;
    }
    float bd0=3e38f,bd1=3e38f,bd2=3e38f,bd3=3e38f,bd4=3e38f,bd5=3e38f,bd6=3e38f,bd7=3e38f,
          bd8=3e38f,bd9=3e38f,bd10=3e38f,bd11=3e38f,bd12=3e38f,bd13=3e38f,bd14=3e38f,bd15=3e38f;
    int   bj0=0,bj1=0,bj2=0,bj3=0,bj4=0,bj5=0,bj6=0,bj7=0,
          bj8=0,bj9=0,bj10=0,bj11=0,bj12=0,bj13=0,bj14=0,bj15=0;

#define DO_ROW(R) {                                                   \
        float dx = px##R - q.x, dy = py##R - q.y;                     \
        float dA = dx * dx + dy * dy;                                 \
        if (dA < bd##R) { bd##R = dA; bj##R = j0; }                   \
        float ex = px##R - q.z, ey = py##R - q.w;                     \
        float dB = ex * ex + ey * ey;                                 \
        if (dB < bd##R) { bd##R = dB; bj##R = j0 + 1; } }

    // this block's j-chunk: float4 indices [c*300 .. (c+1)*300) of 2400
    const int j4end = (c + 1) * (L1 / 2 / JS);
    for (int j4 = c * (L1 / 2 / JS) + tid; j4 < j4end; j4 += 256) {
        const float4 q = p1[j4];
        const int j0 = 2 * j4;
        DO_ROW(0)  DO_ROW(1)  DO_ROW(2)  DO_ROW(3)
        DO_ROW(4)  DO_ROW(5)  DO_ROW(6)  DO_ROW(7)
        DO_ROW(8)  DO_ROW(9)  DO_ROW(10) DO_ROW(11)
        DO_ROW(12) DO_ROW(13) DO_ROW(14) DO_ROW(15)
    }
#undef DO_ROW

    // wave-level min+argmin per row, tie-break smaller j
#define REDUCE_ROW(R) {                                               \
        float d = bd##R; int jj = bj##R;                              \
        for (int off = 32; off; off >>= 1) {                          \
            float od = __shfl_xor(d, off);                            \
            int   oj = __shfl_xor(jj, off);                           \
            if (od < d || (od == d && oj < jj)) { d = od; jj = oj; }  \
        }                                                             \
        if (lane == 0) { redd[R * 4 + wv] = d; redj[R * 4 + wv] = jj; } }

    REDUCE_ROW(0)  REDUCE_ROW(1)  REDUCE_ROW(2)  REDUCE_ROW(3)
    REDUCE_ROW(4)  REDUCE_ROW(5)  REDUCE_ROW(6)  REDUCE_ROW(7)
    REDUCE_ROW(8)  REDUCE_ROW(9)  REDUCE_ROW(10) REDUCE_ROW(11)
    REDUCE_ROW(12) REDUCE_ROW(13) REDUCE_ROW(14) REDUCE_ROW(15)
#undef REDUCE_ROW
    __syncthreads();

    // one packed slot per row: (d2_bits<<32)|j ; u64 min == (min d2, min j)
    if (tid < ROWS) {
        float d = redd[tid * 4 + 0]; int jj = redj[tid * 4 + 0];
        #pragma unroll
        for (int w = 1; w < 4; ++w) {
            float od = redd[tid * 4 + w]; int oj = redj[tid * 4 + w];
            if (od < d || (od == d && oj < jj)) { d = od; jj = oj; }
        }
        slots[(size_t)(gi0 + tid) * JS + c] =
            ((u64)__float_as_uint(d) << 32) | (u32)jj;
    }

    // last-block-done: merge + epilogue + finalize
    if (tid == 0) {
        __threadfence();
        u32 old = atomicAdd(counter, 1u);
        slast = (old == (u32)(NBLK - 1)) ? 1 : 0;
    }
    __syncthreads();
    if (!slast) return;
    __threadfence();

    // mask format detection (first 2400 words in-bounds for all layouts)
    if (tid == 0) sbad = 0u;
    __syncthreads();
    {
        u32 bad = 0u;
        const u32* mwp = (const u32*)maskp;
        for (int i = tid; i < 2400; i += 256) {
            u32 w = mwp[i];
            if (w != 0u && w != 1u && w != 0x3f800000u) bad = 1u;
        }
        atomicOr(&sbad, bad);
    }

    // per-thread accumulation over ~38 rows; all loads independent & pipelined
    float a0=0,a1=0,a2=0,a3=0,a4=0,a5=0,a6=0,a7=0,a8=0,a9=0,a10=0,a11=0;
    for (int gi = tid; gi < NROW; gi += 256) {
        u64 k = slots[(size_t)gi * JS + 0];
        u64 t;
        t = slots[(size_t)gi*JS+1]; if (t < k) k = t;
        t = slots[(size_t)gi*JS+2]; if (t < k) k = t;
        t = slots[(size_t)gi*JS+3]; if (t < k) k = t;
        t = slots[(size_t)gi*JS+4]; if (t < k) k = t;
        t = slots[(size_t)gi*JS+5]; if (t < k) k = t;
        t = slots[(size_t)gi*JS+6]; if (t < k) k = t;
        t = slots[(size_t)gi*JS+7]; if (t < k) k = t;
        const float d2 = __uint_as_float((u32)(k >> 32));
        const int   jj = (int)(u32)(k & 0xffffffffu);
        const float l2 = sqrtf(d2);

        const int nn = (gi >= L0) ? 1 : 0;
        const float2 q0 = ((const float2*)w_pt0)[gi];

        const float thr = 8.0f * scale0[nn * 2 + 0];
        const float sxd = ((float)W1C * scale1[nn * 2 + 0] * 8.0f - 1.0f) * 0.5f;
        const float syd = ((float)H1C * scale1[nn * 2 + 1] * 8.0f - 1.0f) * 0.5f;
        const float* im = score1 + (size_t)nn * L1;

        const float mw = (((const u32*)maskp)[gi] != 0u) ? 1.0f : 0.0f;
        const float mb = (((const unsigned char*)maskp)[gi] != 0) ? 1.0f : 0.0f;
        const float inthr = (l2 <= thr) ? 1.0f : 0.0f;

        const float s0v  = score0[gi];
        const float ssum = im[jj] + s0v;

        const float gx = (q0.x / sxd) * 0.5f * (float)(W1C - 1);
        const float gy = (q0.y / syd) * 0.5f * (float)(H1C - 1);
        const float x0 = floorf(gx), y0 = floorf(gy);
        const float x1 = x0 + 1.0f,  y1 = y0 + 1.0f;
        const float wx1 = gx - x0, wx0 = 1.0f - wx1;
        const float wy1 = gy - y0, wy0 = 1.0f - wy1;

        auto corner = [&](float xf, float yf) -> float {
            bool inb = (xf >= 0.0f) && (xf <= (float)(W1C - 1)) &&
                       (yf >= 0.0f) && (yf <= (float)(H1C - 1));
            int xc = (int)fminf(fmaxf(xf, 0.0f), (float)(W1C - 1));
            int yc = (int)fminf(fmaxf(yf, 0.0f), (float)(H1C - 1));
            float v = im[yc * W1C + xc];
            return inb ? v : 0.0f;
        };
        const float res = corner(x0, y0) * wx0 * wy0
                        + corner(x1, y0) * wx1 * wy0
                        + corner(x0, y1) * wx0 * wy1
                        + corner(x1, y1) * wx1 * wy1;
        const float dsc = res - s0v;
        const float dsq = dsc * dsc;

        const float dvw = inthr * mw, dvb = inthr * mb;
        a0 += dvw;          a1 += l2 * dvw;   a2  += ssum * l2 * dvw;
        a3 += ssum * dvw;   a4 += mw;         a5  += dsq * mw;
        a6 += dvb;          a7 += l2 * dvb;   a8  += ssum * l2 * dvb;
        a9 += ssum * dvb;   a10 += mb;        a11 += dsq * mb;
    }

    // block reduction of the 12 accumulators
#define REDSUM(V, K) {                                                \
        float s = V;                                                  \
        for (int off = 32; off; off >>= 1) s += __shfl_xor(s, off);   \
        if (lane == 0) fin[(K) * 4 + wv] = s; }
    REDSUM(a0,0) REDSUM(a1,1) REDSUM(a2,2)  REDSUM(a3,3)
    REDSUM(a4,4) REDSUM(a5,5) REDSUM(a6,6)  REDSUM(a7,7)
    REDSUM(a8,8) REDSUM(a9,9) REDSUM(a10,10) REDSUM(a11,11)
#undef REDSUM
    __syncthreads();

    if (tid == 0) {
        const int o = (sbad == 0u) ? 0 : 6;   // word-format vs byte-format
        float S0 = fin[(o+0)*4]+fin[(o+0)*4+1]+fin[(o+0)*4+2]+fin[(o+0)*4+3];
        float S1 = fin[(o+1)*4]+fin[(o+1)*4+1]+fin[(o+1)*4+2]+fin[(o+1)*4+3];
        float S2 = fin[(o+2)*4]+fin[(o+2)*4+1]+fin[(o+2)*4+2]+fin[(o+2)*4+3];
        float S3 = fin[(o+3)*4]+fin[(o+3)*4+1]+fin[(o+3)*4+2]+fin[(o+3)*4+3];
        float S4 = fin[(o+4)*4]+fin[(o+4)*4+1]+fin[(o+4)*4+2]+fin[(o+4)*4+3];
        float S5 = fin[(o+5)*4]+fin[(o+5)*4+1]+fin[(o+5)*4+2]+fin[(o+5)*4+3];
        const float den = fmaxf(S0, 1.0f);
        const float lm  = S1 / den;
        out[0] = lm;                              // loc_loss_mean
        out[1] = (S2 - lm * S3) / den;            // rep_loss_mean
        out[2] = 2.0f * S5 / fmaxf(S4, 1.0f);     // score_loss
    }
}

extern "C" void kernel_launch(void* const* d_in, const int* in_sizes, int n_in,
                              void* d_out, int out_size, void* d_ws, size_t ws_size,
                              hipStream_t stream) {
    const float* w_pt0  = (const float*)d_in[0];
    const float* pt1    = (const float*)d_in[1];
    const void*  maskp  =               d_in[2];
    const float* score0 = (const float*)d_in[3];
    const float* score1 = (const float*)d_in[4];
    // d_in[5] = image1 (zeros) -- unused
    const float* scale0 = (const float*)d_in[6];
    const float* scale1 = (const float*)d_in[7];

    u32* counter = (u32*)d_ws;
    u64* slots   = (u64*)((char*)d_ws + 256);   // fully rewritten every call

    hipMemsetAsync(d_ws, 0, 4, stream);         // zero completion counter
    s2ld_main<<<NBLK, 256, 0, stream>>>(w_pt0, pt1, maskp, score0, score1,
                                        scale0, scale1, slots, counter,
                                        (float*)d_out);
}

// Round 6
// 49.222 us; speedup vs baseline: 3.7595x; 3.7595x over previous
//
#include <hip/hip_runtime.h>
#include <math.h>

typedef unsigned long long u64;
typedef unsigned int u32;

#define NB   2
#define L0   4800
#define L1   4800
#define H1C  60
#define W1C  80
#define ROWS 16
#define RPB  (L0 / ROWS)          // 300 row-groups per batch
#define NBLK (NB * RPB)           // 600 blocks
#define L14  (L1 / 2)             // 2400 float4 per batch
// partials layout: k in [0,12): {Sm,Sl2,Ssl2,Ss,Sv,Ssq} x {word-mask, byte-mask}

__global__ __launch_bounds__(256, 4) void s2ld_fused(
    const float* __restrict__ w_pt0,    // [NB][L0][2]
    const float* __restrict__ pt1,      // [NB][L1][2]
    const void*  __restrict__ maskp,    // [NB][L0] word- or byte-bool
    const float* __restrict__ score0,   // [NB][L0]
    const float* __restrict__ score1,   // [NB][L1]
    const float* __restrict__ scale0,   // [NB][2]
    const float* __restrict__ scale1,   // [NB][2]
    float*       __restrict__ partials, // [12][NBLK]
    u32*         __restrict__ counter,
    float*       __restrict__ out)      // [3]
{
    __shared__ float4 sF[L14];          // 38400 B, pt1 tile
    __shared__ float  redd[ROWS * 4];
    __shared__ int    redj[ROWS * 4];
    __shared__ float  fin[12 * 4];
    __shared__ int    slast;
    __shared__ u32    sbad;

    const int tid  = threadIdx.x;
    const int blk  = blockIdx.x;
    const int n    = blk / RPB;
    const int gi0  = n * L0 + (blk % RPB) * ROWS;
    const int lane = tid & 63;
    const int wv   = tid >> 6;

    const float4* p1 = (const float4*)(pt1 + (size_t)n * L1 * 2);
    const float4* p0 = (const float4*)(w_pt0 + (size_t)gi0 * 2);  // 8 float4

    // stage pt1 tile into LDS (float4-wide, one barrier)
    for (int j = tid; j < L14; j += 256) sF[j] = p1[j];

    // 16 query points as NAMED scalars only (arrays => scratch demotion, r2/r3)
    float px0,px1,px2,px3,px4,px5,px6,px7,px8,px9,px10,px11,px12,px13,px14,px15;
    float py0,py1,py2,py3,py4,py5,py6,py7,py8,py9,py10,py11,py12,py13,py14,py15;
    {
        float4 f;
        f=p0[0]; px0 =f.x; py0 =f.y; px1 =f.z; py1 =f.w;
        f=p0[1]; px2 =f.x; py2 =f.y; px3 =f.z; py3 =f.w;
        f=p0[2]; px4 =f.x; py4 =f.y; px5 =f.z; py5 =f.w;
        f=p0[3]; px6 =f.x; py6 =f.y; px7 =f.z; py7 =f.w;
        f=p0[4]; px8 =f.x; py8 =f.y; px9 =f.z; py9 =f.w;
        f=p0[5]; px10=f.x; py10=f.y; px11=f.z; py11=f.w;
        f=p0[6]; px12=f.x; py12=f.y; px13=f.z; py13=f.w;
        f=p0[7]; px14=f.x; py14=f.y; px15=f.z; py15=f.w;
    }
    float bd0=3e38f,bd1=3e38f,bd2=3e38f,bd3=3e38f,bd4=3e38f,bd5=3e38f,bd6=3e38f,bd7=3e38f,
          bd8=3e38f,bd9=3e38f,bd10=3e38f,bd11=3e38f,bd12=3e38f,bd13=3e38f,bd14=3e38f,bd15=3e38f;
    int   bj0=0,bj1=0,bj2=0,bj3=0,bj4=0,bj5=0,bj6=0,bj7=0,
          bj8=0,bj9=0,bj10=0,bj11=0,bj12=0,bj13=0,bj14=0,bj15=0;

    __syncthreads();

#define DO_ROW(R) {                                                   \
        float dx = px##R - q.x, dy = py##R - q.y;                     \
        float dA = dx * dx + dy * dy;                                 \
        if (dA < bd##R) { bd##R = dA; bj##R = j0; }                   \
        float ex = px##R - q.z, ey = py##R - q.w;                     \
        float dB = ex * ex + ey * ey;                                 \
        if (dB < bd##R) { bd##R = dB; bj##R = j0 + 1; } }

    // j ascends per thread => first-occurrence argmin within a thread;
    // cross-thread ties resolved (min d2, then min j) in the reduce.
    for (int j4 = tid; j4 < L14; j4 += 256) {
        const float4 q = sF[j4];
        const int j0 = 2 * j4;
        DO_ROW(0)  DO_ROW(1)  DO_ROW(2)  DO_ROW(3)
        DO_ROW(4)  DO_ROW(5)  DO_ROW(6)  DO_ROW(7)
        DO_ROW(8)  DO_ROW(9)  DO_ROW(10) DO_ROW(11)
        DO_ROW(12) DO_ROW(13) DO_ROW(14) DO_ROW(15)
    }
#undef DO_ROW

#define REDUCE_ROW(R) {                                               \
        float d = bd##R; int jj = bj##R;                              \
        for (int off = 32; off; off >>= 1) {                          \
            float od = __shfl_xor(d, off);                            \
            int   oj = __shfl_xor(jj, off);                           \
            if (od < d || (od == d && oj < jj)) { d = od; jj = oj; }  \
        }                                                             \
        if (lane == 0) { redd[R * 4 + wv] = d; redj[R * 4 + wv] = jj; } }

    REDUCE_ROW(0)  REDUCE_ROW(1)  REDUCE_ROW(2)  REDUCE_ROW(3)
    REDUCE_ROW(4)  REDUCE_ROW(5)  REDUCE_ROW(6)  REDUCE_ROW(7)
    REDUCE_ROW(8)  REDUCE_ROW(9)  REDUCE_ROW(10) REDUCE_ROW(11)
    REDUCE_ROW(12) REDUCE_ROW(13) REDUCE_ROW(14) REDUCE_ROW(15)
#undef REDUCE_ROW
    __syncthreads();

    // parallel epilogue: lane r (< 16, all in wave 0) handles row r
    if (tid < ROWS) {
        const int r = tid;
        float d = redd[r * 4 + 0]; int jj = redj[r * 4 + 0];
        #pragma unroll
        for (int w = 1; w < 4; ++w) {
            float od = redd[r * 4 + w]; int oj = redj[r * 4 + w];
            if (od < d || (od == d && oj < jj)) { d = od; jj = oj; }
        }
        const int gi = gi0 + r;
        const float2 q0 = ((const float2*)w_pt0)[gi];
        const float l2 = sqrtf(d);

        const float thr = 8.0f * scale0[n * 2 + 0];
        const float sxd = ((float)W1C * scale1[n * 2 + 0] * 8.0f - 1.0f) * 0.5f;
        const float syd = ((float)H1C * scale1[n * 2 + 1] * 8.0f - 1.0f) * 0.5f;
        const float* im = score1 + (size_t)n * L1;

        const float mw = (((const u32*)maskp)[gi] != 0u) ? 1.0f : 0.0f;
        const float mb = (((const unsigned char*)maskp)[gi] != 0) ? 1.0f : 0.0f;
        const float inthr = (l2 <= thr) ? 1.0f : 0.0f;

        const float s0v  = score0[gi];
        const float ssum = im[jj] + s0v;

        const float gx = (q0.x / sxd) * 0.5f * (float)(W1C - 1);
        const float gy = (q0.y / syd) * 0.5f * (float)(H1C - 1);
        const float x0 = floorf(gx), y0 = floorf(gy);
        const float x1 = x0 + 1.0f,  y1 = y0 + 1.0f;
        const float wx1 = gx - x0, wx0 = 1.0f - wx1;
        const float wy1 = gy - y0, wy0 = 1.0f - wy1;

        auto corner = [&](float xf, float yf) -> float {
            bool inb = (xf >= 0.0f) && (xf <= (float)(W1C - 1)) &&
                       (yf >= 0.0f) && (yf <= (float)(H1C - 1));
            int xc = (int)fminf(fmaxf(xf, 0.0f), (float)(W1C - 1));
            int yc = (int)fminf(fmaxf(yf, 0.0f), (float)(H1C - 1));
            float v = im[yc * W1C + xc];
            return inb ? v : 0.0f;
        };
        const float res = corner(x0, y0) * wx0 * wy0
                        + corner(x1, y0) * wx1 * wy0
                        + corner(x0, y1) * wx0 * wy1
                        + corner(x1, y1) * wx1 * wy1;
        const float dsc = res - s0v;
        const float dsq = dsc * dsc;

        const float dvw = inthr * mw, dvb = inthr * mb;
        float v0  = dvw,        v1 = l2 * dvw,  v2  = ssum * l2 * dvw;
        float v3  = ssum * dvw, v4 = mw,        v5  = dsq * mw;
        float v6  = dvb,        v7 = l2 * dvb,  v8  = ssum * l2 * dvb;
        float v9  = ssum * dvb, v10 = mb,       v11 = dsq * mb;
#define RED16(V) { V += __shfl_xor(V, 8); V += __shfl_xor(V, 4); \
                   V += __shfl_xor(V, 2); V += __shfl_xor(V, 1); }
        RED16(v0) RED16(v1) RED16(v2) RED16(v3) RED16(v4)  RED16(v5)
        RED16(v6) RED16(v7) RED16(v8) RED16(v9) RED16(v10) RED16(v11)
#undef RED16
        if (tid == 0) {
            partials[ 0 * NBLK + blk] = v0;  partials[ 1 * NBLK + blk] = v1;
            partials[ 2 * NBLK + blk] = v2;  partials[ 3 * NBLK + blk] = v3;
            partials[ 4 * NBLK + blk] = v4;  partials[ 5 * NBLK + blk] = v5;
            partials[ 6 * NBLK + blk] = v6;  partials[ 7 * NBLK + blk] = v7;
            partials[ 8 * NBLK + blk] = v8;  partials[ 9 * NBLK + blk] = v9;
            partials[10 * NBLK + blk] = v10; partials[11 * NBLK + blk] = v11;
        }
    }

    // last-block-done finalize. (old % NBLK)==NBLK-1 fires exactly once per
    // call for ANY initial counter value (calls are stream-serialized), so no
    // per-call memset dispatch is needed.
    if (tid == 0) {
        __threadfence();
        u32 old = atomicAdd(counter, 1u);
        slast = ((old % (u32)NBLK) == (u32)(NBLK - 1)) ? 1 : 0;
    }
    __syncthreads();
    if (!slast) return;
    __threadfence();

    // mask format detection (first 2400 words in-bounds for all layouts)
    if (tid == 0) sbad = 0u;
    __syncthreads();
    {
        u32 bad = 0u;
        const u32* mwp = (const u32*)maskp;
        for (int i = tid; i < 2400; i += 256) {
            u32 w = mwp[i];
            if (w != 0u && w != 1u && w != 0x3f800000u) bad = 1u;
        }
        atomicOr(&sbad, bad);
        __syncthreads();
    }

    // reduce the 12 partial arrays (600 entries each)
    for (int k = 0; k < 12; ++k) {
        float s = 0.0f;
        for (int rbl = tid; rbl < NBLK; rbl += 256) s += partials[k * NBLK + rbl];
        #pragma unroll
        for (int off = 32; off; off >>= 1) s += __shfl_xor(s, off);
        if (lane == 0) fin[k * 4 + wv] = s;
    }
    __syncthreads();

    if (tid == 0) {
        const int o = (sbad == 0u) ? 0 : 6;   // word-format vs byte-format
        float S0 = fin[(o+0)*4]+fin[(o+0)*4+1]+fin[(o+0)*4+2]+fin[(o+0)*4+3];
        float S1 = fin[(o+1)*4]+fin[(o+1)*4+1]+fin[(o+1)*4+2]+fin[(o+1)*4+3];
        float S2 = fin[(o+2)*4]+fin[(o+2)*4+1]+fin[(o+2)*4+2]+fin[(o+2)*4+3];
        float S3 = fin[(o+3)*4]+fin[(o+3)*4+1]+fin[(o+3)*4+2]+fin[(o+3)*4+3];
        float S4 = fin[(o+4)*4]+fin[(o+4)*4+1]+fin[(o+4)*4+2]+fin[(o+4)*4+3];
        float S5 = fin[(o+5)*4]+fin[(o+5)*4+1]+fin[(o+5)*4+2]+fin[(o+5)*4+3];
        const float den = fmaxf(S0, 1.0f);
        const float lm  = S1 / den;
        out[0] = lm;                              // loc_loss_mean
        out[1] = (S2 - lm * S3) / den;            // rep_loss_mean
        out[2] = 2.0f * S5 / fmaxf(S4, 1.0f);     // score_loss
    }
}

extern "C" void kernel_launch(void* const* d_in, const int* in_sizes, int n_in,
                              void* d_out, int out_size, void* d_ws, size_t ws_size,
                              hipStream_t stream) {
    const float* w_pt0  = (const float*)d_in[0];
    const float* pt1    = (const float*)d_in[1];
    const void*  maskp  =               d_in[2];
    const float* score0 = (const float*)d_in[3];
    const float* score1 = (const float*)d_in[4];
    // d_in[5] = image1 (zeros) -- unused
    const float* scale0 = (const float*)d_in[6];
    const float* scale1 = (const float*)d_in[7];

    u32*   counter  = (u32*)d_ws;
    float* partials = (float*)((char*)d_ws + 256);

    s2ld_fused<<<NBLK, 256, 0, stream>>>(w_pt0, pt1, maskp, score0, score1,
                                         scale0, scale1, partials, counter,
                                         (float*)d_out);
}

// Round 7
// 47.785 us; speedup vs baseline: 3.8725x; 1.0301x over previous
//
#include <hip/hip_runtime.h>
#include <math.h>

typedef unsigned long long u64;
typedef unsigned int u32;

#define NB   2
#define L0   4800
#define L1   4800
#define H1C  60
#define W1C  80
#define ROWS 16
#define RPB  (L0 / ROWS)          // 300 row-groups per batch
#define NBLK (NB * RPB)           // 600 blocks
#define NT   512                  // threads per block (8 waves)
#define L14  (L1 / 2)             // 2400 float4 per batch
#define NW   (NT / 64)            // 8 waves
// partials layout: k in [0,12): {Sm,Sl2,Ssl2,Ss,Sv,Ssq} x {word-mask, byte-mask}

__global__ __launch_bounds__(NT, 4) void s2ld_fused(
    const float* __restrict__ w_pt0,    // [NB][L0][2]
    const float* __restrict__ pt1,      // [NB][L1][2]
    const void*  __restrict__ maskp,    // [NB][L0] word- or byte-bool
    const float* __restrict__ score0,   // [NB][L0]
    const float* __restrict__ score1,   // [NB][L1]
    const float* __restrict__ scale0,   // [NB][2]
    const float* __restrict__ scale1,   // [NB][2]
    float*       __restrict__ partials, // [12][NBLK]
    u32*         __restrict__ counter,
    float*       __restrict__ out)      // [3]
{
    __shared__ float4 sF[L14];          // 38400 B, pt1 tile
    __shared__ float  redd[ROWS * NW];
    __shared__ int    redj[ROWS * NW];
    __shared__ float  fin[12 * NW];
    __shared__ int    slast;
    __shared__ u32    sbad;

    const int tid  = threadIdx.x;
    const int blk  = blockIdx.x;
    const int n    = blk / RPB;
    const int gi0  = n * L0 + (blk % RPB) * ROWS;
    const int lane = tid & 63;
    const int wv   = tid >> 6;

    const float4* p1 = (const float4*)(pt1 + (size_t)n * L1 * 2);
    const float4* p0 = (const float4*)(w_pt0 + (size_t)gi0 * 2);  // 8 float4

    // stage pt1 tile into LDS: 4 uniform + 1 ragged load, all independent
    sF[tid]        = p1[tid];
    sF[tid +  512] = p1[tid +  512];
    sF[tid + 1024] = p1[tid + 1024];
    sF[tid + 1536] = p1[tid + 1536];
    if (tid < L14 - 2048) sF[tid + 2048] = p1[tid + 2048];

    // 16 query points as NAMED scalars only (arrays => scratch demotion, r2/r3)
    float px0,px1,px2,px3,px4,px5,px6,px7,px8,px9,px10,px11,px12,px13,px14,px15;
    float py0,py1,py2,py3,py4,py5,py6,py7,py8,py9,py10,py11,py12,py13,py14,py15;
    {
        float4 f;
        f=p0[0]; px0 =f.x; py0 =f.y; px1 =f.z; py1 =f.w;
        f=p0[1]; px2 =f.x; py2 =f.y; px3 =f.z; py3 =f.w;
        f=p0[2]; px4 =f.x; py4 =f.y; px5 =f.z; py5 =f.w;
        f=p0[3]; px6 =f.x; py6 =f.y; px7 =f.z; py7 =f.w;
        f=p0[4]; px8 =f.x; py8 =f.y; px9 =f.z; py9 =f.w;
        f=p0[5]; px10=f.x; py10=f.y; px11=f.z; py11=f.w;
        f=p0[6]; px12=f.x; py12=f.y; px13=f.z; py13=f.w;
        f=p0[7]; px14=f.x; py14=f.y; px15=f.z; py15=f.w;
    }
    float bd0=3e38f,bd1=3e38f,bd2=3e38f,bd3=3e38f,bd4=3e38f,bd5=3e38f,bd6=3e38f,bd7=3e38f,
          bd8=3e38f,bd9=3e38f,bd10=3e38f,bd11=3e38f,bd12=3e38f,bd13=3e38f,bd14=3e38f,bd15=3e38f;
    int   bj0=0,bj1=0,bj2=0,bj3=0,bj4=0,bj5=0,bj6=0,bj7=0,
          bj8=0,bj9=0,bj10=0,bj11=0,bj12=0,bj13=0,bj14=0,bj15=0;

    __syncthreads();

#define DO_ROW(R) {                                                   \
        float dx = px##R - q.x, dy = py##R - q.y;                     \
        float dA = fmaf(dx, dx, dy * dy);                             \
        if (dA < bd##R) { bd##R = dA; bj##R = j0; }                   \
        float ex = px##R - q.z, ey = py##R - q.w;                     \
        float dB = fmaf(ex, ex, ey * ey);                             \
        if (dB < bd##R) { bd##R = dB; bj##R = j0 + 1; } }

#define STEP(J4) {                                                    \
        const float4 q = sF[(J4)];                                    \
        const int j0 = 2 * (J4);                                      \
        DO_ROW(0)  DO_ROW(1)  DO_ROW(2)  DO_ROW(3)                    \
        DO_ROW(4)  DO_ROW(5)  DO_ROW(6)  DO_ROW(7)                    \
        DO_ROW(8)  DO_ROW(9)  DO_ROW(10) DO_ROW(11)                   \
        DO_ROW(12) DO_ROW(13) DO_ROW(14) DO_ROW(15) }

    // j ascends per thread => first-occurrence argmin within a thread;
    // cross-thread ties resolved (min d2, then min j) in the reduce.
    STEP(tid)
    STEP(tid + 512)
    STEP(tid + 1024)
    STEP(tid + 1536)
    if (tid < L14 - 2048) STEP(tid + 2048)
#undef STEP
#undef DO_ROW

#define REDUCE_ROW(R) {                                               \
        float d = bd##R; int jj = bj##R;                              \
        for (int off = 32; off; off >>= 1) {                          \
            float od = __shfl_xor(d, off);                            \
            int   oj = __shfl_xor(jj, off);                           \
            if (od < d || (od == d && oj < jj)) { d = od; jj = oj; }  \
        }                                                             \
        if (lane == 0) { redd[R * NW + wv] = d; redj[R * NW + wv] = jj; } }

    REDUCE_ROW(0)  REDUCE_ROW(1)  REDUCE_ROW(2)  REDUCE_ROW(3)
    REDUCE_ROW(4)  REDUCE_ROW(5)  REDUCE_ROW(6)  REDUCE_ROW(7)
    REDUCE_ROW(8)  REDUCE_ROW(9)  REDUCE_ROW(10) REDUCE_ROW(11)
    REDUCE_ROW(12) REDUCE_ROW(13) REDUCE_ROW(14) REDUCE_ROW(15)
#undef REDUCE_ROW
    __syncthreads();

    // parallel epilogue: lane r (< 16, all in wave 0) handles row r
    if (tid < ROWS) {
        const int r = tid;
        float d = redd[r * NW + 0]; int jj = redj[r * NW + 0];
        #pragma unroll
        for (int w = 1; w < NW; ++w) {
            float od = redd[r * NW + w]; int oj = redj[r * NW + w];
            if (od < d || (od == d && oj < jj)) { d = od; jj = oj; }
        }
        const int gi = gi0 + r;
        const float2 q0 = ((const float2*)w_pt0)[gi];
        const float l2 = sqrtf(d);

        const float thr = 8.0f * scale0[n * 2 + 0];
        const float sxd = ((float)W1C * scale1[n * 2 + 0] * 8.0f - 1.0f) * 0.5f;
        const float syd = ((float)H1C * scale1[n * 2 + 1] * 8.0f - 1.0f) * 0.5f;
        const float* im = score1 + (size_t)n * L1;

        const float mw = (((const u32*)maskp)[gi] != 0u) ? 1.0f : 0.0f;
        const float mb = (((const unsigned char*)maskp)[gi] != 0) ? 1.0f : 0.0f;
        const float inthr = (l2 <= thr) ? 1.0f : 0.0f;

        const float s0v  = score0[gi];
        const float ssum = im[jj] + s0v;

        const float gx = (q0.x / sxd) * 0.5f * (float)(W1C - 1);
        const float gy = (q0.y / syd) * 0.5f * (float)(H1C - 1);
        const float x0 = floorf(gx), y0 = floorf(gy);
        const float x1 = x0 + 1.0f,  y1 = y0 + 1.0f;
        const float wx1 = gx - x0, wx0 = 1.0f - wx1;
        const float wy1 = gy - y0, wy0 = 1.0f - wy1;

        auto corner = [&](float xf, float yf) -> float {
            bool inb = (xf >= 0.0f) && (xf <= (float)(W1C - 1)) &&
                       (yf >= 0.0f) && (yf <= (float)(H1C - 1));
            int xc = (int)fminf(fmaxf(xf, 0.0f), (float)(W1C - 1));
            int yc = (int)fminf(fmaxf(yf, 0.0f), (float)(H1C - 1));
            float v = im[yc * W1C + xc];
            return inb ? v : 0.0f;
        };
        const float res = corner(x0, y0) * wx0 * wy0
                        + corner(x1, y0) * wx1 * wy0
                        + corner(x0, y1) * wx0 * wy1
                        + corner(x1, y1) * wx1 * wy1;
        const float dsc = res - s0v;
        const float dsq = dsc * dsc;

        const float dvw = inthr * mw, dvb = inthr * mb;
        float v0  = dvw,        v1 = l2 * dvw,  v2  = ssum * l2 * dvw;
        float v3  = ssum * dvw, v4 = mw,        v5  = dsq * mw;
        float v6  = dvb,        v7 = l2 * dvb,  v8  = ssum * l2 * dvb;
        float v9  = ssum * dvb, v10 = mb,       v11 = dsq * mb;
#define RED16(V) { V += __shfl_xor(V, 8); V += __shfl_xor(V, 4); \
                   V += __shfl_xor(V, 2); V += __shfl_xor(V, 1); }
        RED16(v0) RED16(v1) RED16(v2) RED16(v3) RED16(v4)  RED16(v5)
        RED16(v6) RED16(v7) RED16(v8) RED16(v9) RED16(v10) RED16(v11)
#undef RED16
        if (tid == 0) {
            partials[ 0 * NBLK + blk] = v0;  partials[ 1 * NBLK + blk] = v1;
            partials[ 2 * NBLK + blk] = v2;  partials[ 3 * NBLK + blk] = v3;
            partials[ 4 * NBLK + blk] = v4;  partials[ 5 * NBLK + blk] = v5;
            partials[ 6 * NBLK + blk] = v6;  partials[ 7 * NBLK + blk] = v7;
            partials[ 8 * NBLK + blk] = v8;  partials[ 9 * NBLK + blk] = v9;
            partials[10 * NBLK + blk] = v10; partials[11 * NBLK + blk] = v11;
        }
    }

    // last-block-done finalize. (old % NBLK)==NBLK-1 fires exactly once per
    // call for ANY initial counter value (calls are stream-serialized).
    if (tid == 0) {
        __threadfence();
        u32 old = atomicAdd(counter, 1u);
        slast = ((old % (u32)NBLK) == (u32)(NBLK - 1)) ? 1 : 0;
    }
    __syncthreads();
    if (!slast) return;
    __threadfence();

    // mask format detection (first 2400 words in-bounds for all layouts)
    if (tid == 0) sbad = 0u;
    __syncthreads();
    {
        u32 bad = 0u;
        const u32* mwp = (const u32*)maskp;
        for (int i = tid; i < 2400; i += NT) {
            u32 w = mwp[i];
            if (w != 0u && w != 1u && w != 0x3f800000u) bad = 1u;
        }
        atomicOr(&sbad, bad);
        __syncthreads();
    }

    // reduce the 12 partial arrays (600 entries each)
    for (int k = 0; k < 12; ++k) {
        float s = 0.0f;
        for (int rbl = tid; rbl < NBLK; rbl += NT) s += partials[k * NBLK + rbl];
        #pragma unroll
        for (int off = 32; off; off >>= 1) s += __shfl_xor(s, off);
        if (lane == 0) fin[k * NW + wv] = s;
    }
    __syncthreads();

    if (tid == 0) {
        const int o = (sbad == 0u) ? 0 : 6;   // word-format vs byte-format
        float S[6];
        #pragma unroll
        for (int k = 0; k < 6; ++k) {
            float s = 0.0f;
            #pragma unroll
            for (int w = 0; w < NW; ++w) s += fin[(o + k) * NW + w];
            S[k] = s;
        }
        const float den = fmaxf(S[0], 1.0f);
        const float lm  = S[1] / den;
        out[0] = lm;                              // loc_loss_mean
        out[1] = (S[2] - lm * S[3]) / den;        // rep_loss_mean
        out[2] = 2.0f * S[5] / fmaxf(S[4], 1.0f); // score_loss
    }
}

extern "C" void kernel_launch(void* const* d_in, const int* in_sizes, int n_in,
                              void* d_out, int out_size, void* d_ws, size_t ws_size,
                              hipStream_t stream) {
    const float* w_pt0  = (const float*)d_in[0];
    const float* pt1    = (const float*)d_in[1];
    const void*  maskp  =               d_in[2];
    const float* score0 = (const float*)d_in[3];
    const float* score1 = (const float*)d_in[4];
    // d_in[5] = image1 (zeros) -- unused
    const float* scale0 = (const float*)d_in[6];
    const float* scale1 = (const float*)d_in[7];

    u32*   counter  = (u32*)d_ws;
    float* partials = (float*)((char*)d_ws + 256);

    s2ld_fused<<<NBLK, NT, 0, stream>>>(w_pt0, pt1, maskp, score0, score1,
                                        scale0, scale1, partials, counter,
                                        (float*)d_out);
}